// Round 1
// baseline (339.282 us; speedup 1.0000x reference)
//
#include <hip/hip_runtime.h>
#include <math.h>

// Stage 1: per-edge factor->var messages + scatter into var accumulator.
__global__ void __launch_bounds__(256) k1_f2v(
    const float* __restrict__ fbel,   // [F*32] factor_beliefs
    const float* __restrict__ pv2f,   // [E*2]  prv var->factor msgs
    const int*   __restrict__ fidx,   // [E]
    const int*   __restrict__ vidx,   // [E]
    const int*   __restrict__ evidx,  // [E] axis in [0,5)
    float* __restrict__ f2v_out,      // [E*2]
    float* __restrict__ vacc,         // [V*2] (pre-zeroed)
    int E)
{
    int e = blockIdx.x * 256 + threadIdx.x;
    if (e >= E) return;
    int f   = fidx[e];
    int bit = 4 - evidx[e];           // flat-index bit for axis d+1 (row-major)

    const float4* tab = reinterpret_cast<const float4*>(fbel + (size_t)f * 32);
    float v[32];
#pragma unroll
    for (int q = 0; q < 8; ++q) {
        float4 t = tab[q];
        v[q*4+0] = t.x; v[q*4+1] = t.y; v[q*4+2] = t.z; v[q*4+3] = t.w;
    }

    float m0 = -INFINITY, m1 = -INFINITY;
#pragma unroll
    for (int j = 0; j < 32; ++j) {
        bool hi = (j >> bit) & 1;
        if (hi) m1 = fmaxf(m1, v[j]); else m0 = fmaxf(m0, v[j]);
    }
    float s0 = 0.f, s1 = 0.f;
#pragma unroll
    for (int j = 0; j < 32; ++j) {
        bool hi = (j >> bit) & 1;
        float ex = __expf(v[j] - (hi ? m1 : m0));
        if (hi) s1 += ex; else s0 += ex;
    }
    float marg0 = m0 + __logf(s0);
    float marg1 = m1 + __logf(s1);

    float p0 = pv2f[2*e],   p1 = pv2f[2*e+1];
    p0 = (p0 == -INFINITY) ? 0.f : p0;
    p1 = (p1 == -INFINITY) ? 0.f : p1;
    float r0 = marg0 - p0, r1 = marg1 - p1;

    f2v_out[2*e]   = r0;
    f2v_out[2*e+1] = r1;

    int vi = vidx[e];
    atomicAdd(&vacc[2*vi],   r0);
    atomicAdd(&vacc[2*vi+1], r1);
}

// Stage 2: normalize var beliefs in place (log-softmax over 2 states).
__global__ void __launch_bounds__(256) k2_varnorm(float* __restrict__ vb, int V)
{
    int v = blockIdx.x * 256 + threadIdx.x;
    if (v >= V) return;
    float a0 = vb[2*v], a1 = vb[2*v+1];
    float m = fmaxf(a0, a1);
    float l = m + __logf(__expf(a0 - m) + __expf(a1 - m));
    vb[2*v]   = a0 - l;
    vb[2*v+1] = a1 - l;
}

// Stage 3: per-edge var->factor messages + scatter into per-(factor,axis) acc.
__global__ void __launch_bounds__(256) k3_v2f(
    const float* __restrict__ vb,     // [V*2] normalized var beliefs
    const float* __restrict__ pf2v,   // [E*2] prv factor->var msgs
    const int*   __restrict__ fidx,
    const int*   __restrict__ vidx,
    const int*   __restrict__ evidx,
    float* __restrict__ v2f_out,      // [E*2]
    float* __restrict__ facc,         // [F*10] (pre-zeroed) layout [f][d][x]
    int E)
{
    int e = blockIdx.x * 256 + threadIdx.x;
    if (e >= E) return;
    int vi = vidx[e];
    float b0 = vb[2*vi], b1 = vb[2*vi+1];
    float p0 = pf2v[2*e], p1 = pf2v[2*e+1];
    p0 = (p0 == -INFINITY) ? 0.f : p0;
    p1 = (p1 == -INFINITY) ? 0.f : p1;
    float r0 = b0 - p0, r1 = b1 - p1;

    v2f_out[2*e]   = r0;
    v2f_out[2*e+1] = r1;

    int f = fidx[e], d = evidx[e];
    atomicAdd(&facc[(size_t)f*10 + d*2    ], r0);
    atomicAdd(&facc[(size_t)f*10 + d*2 + 1], r1);
}

// Stage 4: reconstruct 32-entry factor beliefs from 5 axis-pairs, add
// potentials, log-softmax over the 32 entries.
__global__ void __launch_bounds__(256) k4_fb(
    const float* __restrict__ facc,   // [F*10]
    const float* __restrict__ pot,    // [F*32]
    float* __restrict__ fb_out,       // [F*32]
    int F)
{
    int f = blockIdx.x * 256 + threadIdx.x;
    if (f >= F) return;

    float a[10];
#pragma unroll
    for (int i = 0; i < 10; ++i) a[i] = facc[(size_t)f*10 + i];

    float t[32];
    const float4* pp = reinterpret_cast<const float4*>(pot + (size_t)f * 32);
#pragma unroll
    for (int q = 0; q < 8; ++q) {
        float4 x = pp[q];
        t[q*4+0] = x.x; t[q*4+1] = x.y; t[q*4+2] = x.z; t[q*4+3] = x.w;
    }

    float m = -INFINITY;
#pragma unroll
    for (int j = 0; j < 32; ++j) {
        float s = t[j];
#pragma unroll
        for (int d = 0; d < 5; ++d) s += a[d*2 + ((j >> (4 - d)) & 1)];
        t[j] = s;
        m = fmaxf(m, s);
    }
    float sum = 0.f;
#pragma unroll
    for (int j = 0; j < 32; ++j) sum += __expf(t[j] - m);
    float l = m + __logf(sum);

    float4* out = reinterpret_cast<float4*>(fb_out + (size_t)f * 32);
#pragma unroll
    for (int q = 0; q < 8; ++q) {
        float4 x;
        x.x = t[q*4+0] - l; x.y = t[q*4+1] - l;
        x.z = t[q*4+2] - l; x.w = t[q*4+3] - l;
        out[q] = x;
    }
}

extern "C" void kernel_launch(void* const* d_in, const int* in_sizes, int n_in,
                              void* d_out, int out_size, void* d_ws, size_t ws_size,
                              hipStream_t stream)
{
    const float* fbel  = (const float*)d_in[0];   // factor_beliefs [F,32]
    // d_in[1] var_beliefs: unused by the reference computation (shape only)
    const float* pot   = (const float*)d_in[2];   // factor_potentials [F,32]
    const float* pv2f  = (const float*)d_in[3];   // prv v->f msgs [E,2]
    const float* pf2v  = (const float*)d_in[4];   // prv f->v msgs [E,2]
    const int*   fidx  = (const int*)d_in[5];
    const int*   vidx  = (const int*)d_in[6];
    const int*   evidx = (const int*)d_in[7];

    const int E  = in_sizes[5];
    const int F_ = in_sizes[0] / 32;
    const int V_ = in_sizes[1] / 2;

    float* out     = (float*)d_out;
    float* var_out = out;                          // [V*2]
    float* fb_out  = out + (size_t)V_ * 2;         // [F*32]
    float* f2v_out = fb_out + (size_t)F_ * 32;     // [E*2]
    float* v2f_out = f2v_out + (size_t)E * 2;      // [E*2]

    float* facc = (float*)d_ws;                    // [F*10]

    // Accumulators are poisoned (0xAA) before every timed launch -> zero them.
    hipMemsetAsync(var_out, 0, (size_t)V_ * 2 * sizeof(float), stream);
    hipMemsetAsync(facc,    0, (size_t)F_ * 10 * sizeof(float), stream);

    k1_f2v    <<<dim3((E  + 255) / 256), dim3(256), 0, stream>>>(
        fbel, pv2f, fidx, vidx, evidx, f2v_out, var_out, E);
    k2_varnorm<<<dim3((V_ + 255) / 256), dim3(256), 0, stream>>>(var_out, V_);
    k3_v2f    <<<dim3((E  + 255) / 256), dim3(256), 0, stream>>>(
        var_out, pf2v, fidx, vidx, evidx, v2f_out, facc, E);
    k4_fb     <<<dim3((F_ + 255) / 256), dim3(256), 0, stream>>>(
        facc, pot, fb_out, F_);
}